// Round 10
// baseline (125.305 us; speedup 1.0000x reference)
//
#include <hip/hip_runtime.h>

typedef float f32x16 __attribute__((ext_vector_type(16)));
typedef float f32x4  __attribute__((ext_vector_type(4)));
typedef float f32x2  __attribute__((ext_vector_type(2)));
typedef short bf16x8 __attribute__((ext_vector_type(8)));

#define NB 16
#define CI 64
#define CO 64
#define Hh 128
#define Ww 128

// A in 32x32x16-fragment order: short index ((tap*4+ks)*8 + mg)*512 + l*8 + e
// M-remap (px in-lane): m = mg*32 + r ; py = mg>>2, och = mg&3, oc = och*16 + (r>>1), px = r&1
// k: ic = ks*16 + (l>>5)*8 + e
__device__ short g_A[9 * 4 * 8 * 64 * 8];            // 288 KB (L2-resident)
__device__ short g_xh[(size_t)NB * Hh * Ww * CI];    // x in NHWC bf16, 33.5 MB

__device__ inline short f2bf(float f) {
  union { float f; unsigned u; } v; v.f = f;
  unsigned r = (v.u + 0x7FFF + ((v.u >> 16) & 1)) >> 16;   // RNE
  return (short)r;
}

__global__ __launch_bounds__(256) void build_filters(const float* __restrict__ w) {
  const int ef = blockIdx.x * 256 + threadIdx.x;
  if (ef >= 147456) return;
  const int e   = ef & 7;
  const int l   = (ef >> 3) & 63;
  const int mg  = (ef >> 9) & 7;
  const int ks  = (ef >> 12) & 3;
  const int tap = ef >> 14;
  const int r   = l & 31;
  const int px  = r & 1;
  const int py  = mg >> 2;
  const int oc  = (mg & 3) * 16 + (r >> 1);
  const int ic  = ks * 16 + (l >> 5) * 8 + e;
  const int dyi = tap / 3, dxi = tap % 3;
  const int my = 2 * dyi + 1 - py;          // composite 6-tap index for this parity
  const int mx = 2 * dxi + 1 - px;
  const float FF[4] = {0.25f, 0.75f, 0.75f, 0.25f}; // [1,3,3,1]/4 incl. up^2 gain
  const float* wp = w + (oc * CI + ic) * 9;
  float s = 0.f;
  #pragma unroll
  for (int ky = 0; ky < 3; ++ky) {
    const int iy = my - ky;
    if (iy < 0 || iy > 3) continue;
    #pragma unroll
    for (int kx = 0; kx < 3; ++kx) {
      const int ix = mx - kx;
      if (ix < 0 || ix > 3) continue;
      s += wp[(2 - ky) * 3 + (2 - kx)] * (FF[iy] * FF[ix]); // true conv: flipped w
    }
  }
  g_A[ef] = f2bf(s * (1.0f / 24.0f));       // WEIGHT_GAIN = 1/sqrt(64*9)
}

// NCHW fp32 -> NHWC bf16 via LDS transpose, coalesced both sides.
__global__ __launch_bounds__(256) void to_nhwc(const float* __restrict__ x) {
  __shared__ alignas(16) char xt[64 * 512];          // 32 KB fp32, XOR-granule swizzle
  const int b = blockIdx.x;                 // (n, y)
  const int n = b >> 7, y = b & 127;
  const int tid = threadIdx.x;
  #pragma unroll
  for (int it = 0; it < 8; ++it) {
    const int idx = tid + it * 256;         // 0..2047 float4 units
    const int ic = idx >> 5, xq = idx & 31;
    const f32x4 v = *(const f32x4*)(x + (((size_t)n * CI + ic) * Hh + y) * Ww + xq * 4);
    *(f32x4*)(xt + ic * 512 + ((xq * 16) ^ (((ic >> 3) & 7) * 16))) = v;
  }
  __syncthreads();
  #pragma unroll
  for (int it = 0; it < 4; ++it) {
    const int idx = tid + it * 256;         // 0..1023
    const int icb = idx & 7, xp = idx >> 3; // xp 0..127
    bf16x8 o;
    #pragma unroll
    for (int j = 0; j < 8; ++j) {
      const int ic = icb * 8 + j;
      const float f = *(const float*)(xt + ic * 512 + (((xp >> 2) * 16) ^ (icb * 16)) + (xp & 3) * 4);
      o[j] = f2bf(f);
    }
    *(bf16x8*)(g_xh + (((size_t)n * Hh + y) * Ww + xp) * CI + icb * 8) = o;
  }
}

// Main conv: block = 256 thr (4 waves = wm2 x wn2), M=128 (zs-slice) x N=256 (64p x 4q).
// Wave = mf2 x nf4 -> per-wave A demand halved vs R4 (L2 ceiling fix). Barrier-free
// tap loop with A-from-L2 register reloads; NT f32x2 stores (256-B dense segments).
#define CH 6352   // 6 rows * 66 pix * 16 B + 16 pad

__global__ __launch_bounds__(256, 2) void mfma_conv(const float* __restrict__ bias,
                                                    float* __restrict__ out) {
  __shared__ alignas(16) char xs[8 * CH];   // 50816 B

  const int tid = threadIdx.x;
  const int l   = tid & 63;
  const int wid = tid >> 6;                 // 4 waves
  const int wm  = wid >> 1;                 // M pair within slice
  const int wn  = wid & 1;                  // N half (q pair)
  const int n   = blockIdx.y;
  const int zs  = blockIdx.x & 1;           // M-slice: mg in {4zs..4zs+3}; py = zs
  const int pt  = (blockIdx.x >> 1) & 1;
  const int qt  = blockIdx.x >> 2;          // 0..31
  const int qb  = qt * 4, pb = pt * 64;

  // ---- issue tap-0 A-fragment loads early (latency hides under staging) ----
  bf16x8 a[4][2];                           // [ks][mf], mg = zs*4 + wm*2 + mf
  #pragma unroll
  for (int ks = 0; ks < 4; ++ks)
    #pragma unroll
    for (int mf = 0; mf < 2; ++mf)
      a[ks][mf] = *(const bf16x8*)(g_A + (ks * 8 + zs * 4 + wm * 2 + mf) * 512 + l * 8);

  // ---- stage 6x66x64 halo into chunked LDS ----
  const size_t xbase = (size_t)n * (Hh * Ww * CI);
  for (int u = tid; u < 3168; u += 256) {   // 396 pix * 8 chunks
    const int icb8 = u & 7, pix = u >> 3;
    const int yy = pix / 66, xx = pix - yy * 66;
    const int gy = qb - 1 + yy, gx = pb - 1 + xx;
    bf16x8 v = {};
    if ((unsigned)gy < (unsigned)Hh && (unsigned)gx < (unsigned)Ww)
      v = *(const bf16x8*)(g_xh + xbase + (size_t)(gy * Ww + gx) * CI + icb8 * 8);
    *(bf16x8*)(xs + icb8 * CH + pix * 16) = v;
  }
  __syncthreads();                          // the only barrier

  f32x16 acc[2][4];
  #pragma unroll
  for (int mf = 0; mf < 2; ++mf)
    #pragma unroll
    for (int nf = 0; nf < 4; ++nf)
      #pragma unroll
      for (int r = 0; r < 16; ++r) acc[mf][nf][r] = 0.f;

  const int col = l & 31, kg2 = l >> 5;
  // pos = wn*128 + nf*32 + col -> q = wn*2 + (nf>>1), p = (nf&1)*32 + col
  int bbase[4];
  #pragma unroll
  for (int nf = 0; nf < 4; ++nf) {
    const int q = wn * 2 + (nf >> 1);
    const int p = (nf & 1) * 32 + col;
    bbase[nf] = kg2 * CH + (q * 66 + p) * 16;
  }

  #pragma unroll
  for (int tap = 0; tap < 9; ++tap) {
    const int dyi = tap / 3, dxi = tap % 3;
    const int bsh = (dyi * 66 + dxi) * 16;
    #pragma unroll
    for (int ks = 0; ks < 4; ++ks) {
      bf16x8 b[4];
      #pragma unroll
      for (int nf = 0; nf < 4; ++nf)
        b[nf] = *(const bf16x8*)(xs + bbase[nf] + ks * (2 * CH) + bsh);
      __builtin_amdgcn_s_setprio(1);
      #pragma unroll
      for (int mf = 0; mf < 2; ++mf)
        #pragma unroll
        for (int nf = 0; nf < 4; ++nf)
          acc[mf][nf] = __builtin_amdgcn_mfma_f32_32x32x16_bf16(a[ks][mf], b[nf], acc[mf][nf], 0, 0, 0);
      __builtin_amdgcn_s_setprio(0);
      if (tap < 8) {                        // reload a[ks] for tap+1 (regs just freed)
        #pragma unroll
        for (int mf = 0; mf < 2; ++mf)
          a[ks][mf] = *(const bf16x8*)(g_A + (((tap + 1) * 4 + ks) * 8 + zs * 4 + wm * 2 + mf) * 512 + l * 8);
      }
    }
  }

  // ---- epilogue: bias + lrelu*sqrt2 + clamp; in-lane px pairs -> dense f32x2 NT stores ----
  float* outp = out + ((size_t)(n * CO) << 16);
  #pragma unroll
  for (int mf = 0; mf < 2; ++mf) {
    const int och = wm * 2 + mf;            // mg = zs*4 + och, py = zs
    #pragma unroll
    for (int nf = 0; nf < 4; ++nf) {
      const int q = wn * 2 + (nf >> 1);
      const int y = 2 * (qb + q) + zs;
      const int xd = 2 * (pb + (nf & 1) * 32 + col);
      #pragma unroll
      for (int rp = 0; rp < 8; ++rp) {
        const int oc = och * 16 + (rp & 1) + 4 * (rp >> 1) + 2 * kg2;
        const float bj = bias[oc];
        float v0 = acc[mf][nf][2 * rp]     + bj;
        float v1 = acc[mf][nf][2 * rp + 1] + bj;
        v0 = (v0 >= 0.f ? v0 : 0.2f * v0) * 1.4142135623730951f;
        v1 = (v1 >= 0.f ? v1 : 0.2f * v1) * 1.4142135623730951f;
        v0 = fminf(256.f, fmaxf(-256.f, v0));
        v1 = fminf(256.f, fmaxf(-256.f, v1));
        f32x2 o; o[0] = v0; o[1] = v1;
        __builtin_nontemporal_store(o, (f32x2*)(outp + ((size_t)oc << 16) + y * 256 + xd));
      }
    }
  }
}

extern "C" void kernel_launch(void* const* d_in, const int* in_sizes, int n_in,
                              void* d_out, int out_size, void* d_ws, size_t ws_size,
                              hipStream_t stream) {
  const float* x    = (const float*)d_in[0];
  const float* w    = (const float*)d_in[1];
  const float* bias = (const float*)d_in[2];
  float* out = (float*)d_out;

  build_filters<<<576, 256, 0, stream>>>(w);
  to_nhwc<<<2048, 256, 0, stream>>>(x);
  mfma_conv<<<dim3(128, NB), 256, 0, stream>>>(bias, out);
}

// Round 11
// 117.686 us; speedup vs baseline: 1.0647x; 1.0647x over previous
//
#include <hip/hip_runtime.h>

typedef float f32x16 __attribute__((ext_vector_type(16)));
typedef float f32x4  __attribute__((ext_vector_type(4)));
typedef float f32x2  __attribute__((ext_vector_type(2)));
typedef short bf16x8 __attribute__((ext_vector_type(8)));

#define NB 16
#define CI 64
#define CO 64
#define Hh 128
#define Ww 128

// A in 32x32x16-fragment order: short index ((tap*4+ks)*8 + mg)*512 + l*8 + e
// M-remap (px in-lane): m = mg*32 + r ; py = mg>>2, och = mg&3, oc = och*16 + (r>>1), px = r&1
// k: ic = ks*16 + (l>>5)*8 + e
__device__ short g_A[9 * 4 * 8 * 64 * 8];            // 288 KB (L2-resident)
__device__ short g_xh[(size_t)NB * Hh * Ww * CI];    // x in NHWC bf16, 33.5 MB

__device__ inline short f2bf(float f) {
  union { float f; unsigned u; } v; v.f = f;
  unsigned r = (v.u + 0x7FFF + ((v.u >> 16) & 1)) >> 16;   // RNE
  return (short)r;
}

// Merged prep: blocks [0,2048) = NCHW fp32 -> NHWC bf16 transpose; [2048,2112) = filters.
__global__ __launch_bounds__(256) void prep(const float* __restrict__ x,
                                            const float* __restrict__ w) {
  const int tid = threadIdx.x;
  if (blockIdx.x >= 2048) {
    const int base = (blockIdx.x - 2048) * 2304;
    #pragma unroll
    for (int i = 0; i < 9; ++i) {
      const int ef = base + i * 256 + tid;
      const int e   = ef & 7;
      const int l   = (ef >> 3) & 63;
      const int mg  = (ef >> 9) & 7;
      const int ks  = (ef >> 12) & 3;
      const int tap = ef >> 14;
      const int r   = l & 31;
      const int px  = r & 1;
      const int py  = mg >> 2;
      const int oc  = (mg & 3) * 16 + (r >> 1);
      const int ic  = ks * 16 + (l >> 5) * 8 + e;
      const int dyi = tap / 3, dxi = tap % 3;
      const int my = 2 * dyi + 1 - py;      // composite 6-tap index for this parity
      const int mx = 2 * dxi + 1 - px;
      const float FF[4] = {0.25f, 0.75f, 0.75f, 0.25f}; // [1,3,3,1]/4 incl. up^2 gain
      const float* wp = w + (oc * CI + ic) * 9;
      float s = 0.f;
      #pragma unroll
      for (int ky = 0; ky < 3; ++ky) {
        const int iy = my - ky;
        if (iy < 0 || iy > 3) continue;
        #pragma unroll
        for (int kx = 0; kx < 3; ++kx) {
          const int ix = mx - kx;
          if (ix < 0 || ix > 3) continue;
          s += wp[(2 - ky) * 3 + (2 - kx)] * (FF[iy] * FF[ix]); // true conv: flipped w
        }
      }
      g_A[ef] = f2bf(s * (1.0f / 24.0f));   // WEIGHT_GAIN = 1/sqrt(64*9)
    }
    return;
  }
  // ---- NCHW -> NHWC via LDS transpose, coalesced both sides ----
  __shared__ alignas(16) char xt[64 * 512];          // 32 KB fp32, XOR-granule swizzle
  const int b = blockIdx.x;                 // (n, y)
  const int n = b >> 7, y = b & 127;
  #pragma unroll
  for (int it = 0; it < 8; ++it) {
    const int idx = tid + it * 256;         // 0..2047 float4 units
    const int ic = idx >> 5, xq = idx & 31;
    const f32x4 v = *(const f32x4*)(x + (((size_t)n * CI + ic) * Hh + y) * Ww + xq * 4);
    *(f32x4*)(xt + ic * 512 + ((xq * 16) ^ (((ic >> 3) & 7) * 16))) = v;
  }
  __syncthreads();
  #pragma unroll
  for (int it = 0; it < 4; ++it) {
    const int idx = tid + it * 256;         // 0..1023
    const int icb = idx & 7, xp = idx >> 3; // xp 0..127
    bf16x8 o;
    #pragma unroll
    for (int j = 0; j < 8; ++j) {
      const int ic = icb * 8 + j;
      const float f = *(const float*)(xt + ic * 512 + (((xp >> 2) * 16) ^ (icb * 16)) + (xp & 3) * 4);
      o[j] = f2bf(f);
    }
    *(bf16x8*)(g_xh + (((size_t)n * Hh + y) * Ww + xp) * CI + icb * 8) = o;
  }
}

// Main conv (R4 geometry, verbatim): block = 256 thr (4 waves = wm2 x wn2),
// M=256 x N=128 (16p x 8q pos tile). Wave = mf4 x nf2. A in regs reloaded from L2;
// B (xs halo) in LDS; single barrier; NT f32x2 stores (in-lane px pairs).
#define CH_STR 2896   // 180 pix * 16B + 16 pad

__global__ __launch_bounds__(256, 2) void mfma_conv(const float* __restrict__ bias,
                                                    float* __restrict__ out) {
  __shared__ alignas(16) char xs[8 * CH_STR];        // 23168 B

  const int tid = threadIdx.x;
  const int l   = tid & 63;
  const int wid = tid >> 6;                 // 4 waves
  const int wm  = wid >> 1;                 // M half (mg = wm*4 + mf)
  const int wn  = wid & 1;                  // N half
  const int n   = blockIdx.y;
  const int ty0 = blockIdx.x >> 3, tx0 = blockIdx.x & 7;
  const int qb  = ty0 * 8, pb = tx0 * 16;

  // ---- issue tap-0 A-fragment loads early (latency hides under staging) ----
  bf16x8 a[4][4];                           // [ks][mf]
  #pragma unroll
  for (int ks = 0; ks < 4; ++ks)
    #pragma unroll
    for (int mf = 0; mf < 4; ++mf)
      a[ks][mf] = *(const bf16x8*)(g_A + (ks * 8 + wm * 4 + mf) * 512 + l * 8);

  // ---- stage 10x18x64 halo into chunked LDS ----
  const size_t xbase = (size_t)n * (Hh * Ww * CI);
  for (int u = tid; u < 1440; u += 256) {   // 180 pix * 8 chunks
    const int icb8 = u & 7, pix = u >> 3;
    const int yy = pix / 18, xx = pix - yy * 18;
    const int gy = qb - 1 + yy, gx = pb - 1 + xx;
    bf16x8 v = {};
    if ((unsigned)gy < (unsigned)Hh && (unsigned)gx < (unsigned)Ww)
      v = *(const bf16x8*)(g_xh + xbase + (size_t)(gy * Ww + gx) * CI + icb8 * 8);
    *(bf16x8*)(xs + icb8 * CH_STR + pix * 16) = v;
  }
  __syncthreads();                          // the only barrier

  f32x16 acc[4][2];
  #pragma unroll
  for (int mf = 0; mf < 4; ++mf)
    #pragma unroll
    for (int nf = 0; nf < 2; ++nf)
      #pragma unroll
      for (int r = 0; r < 16; ++r) acc[mf][nf][r] = 0.f;

  const int col = l & 31, kg2 = l >> 5;
  const int p = col & 15, qh = col >> 4;    // pos = wn*64 + nf*32 + col -> q, p
  int bbase[2];
  #pragma unroll
  for (int nf = 0; nf < 2; ++nf)
    bbase[nf] = kg2 * CH_STR + ((wn * 4 + nf * 2 + qh) * 18 + p) * 16;

  #pragma unroll
  for (int tap = 0; tap < 9; ++tap) {
    const int dyi = tap / 3, dxi = tap % 3;
    const int bsh = (dyi * 18 + dxi) * 16;
    #pragma unroll
    for (int ks = 0; ks < 4; ++ks) {
      bf16x8 b[2];
      #pragma unroll
      for (int nf = 0; nf < 2; ++nf)
        b[nf] = *(const bf16x8*)(xs + bbase[nf] + ks * (2 * CH_STR) + bsh);
      __builtin_amdgcn_s_setprio(1);
      #pragma unroll
      for (int mf = 0; mf < 4; ++mf)
        #pragma unroll
        for (int nf = 0; nf < 2; ++nf)
          acc[mf][nf] = __builtin_amdgcn_mfma_f32_32x32x16_bf16(a[ks][mf], b[nf], acc[mf][nf], 0, 0, 0);
      __builtin_amdgcn_s_setprio(0);
      if (tap < 8) {                        // reload a[ks] for tap+1 (regs just freed)
        #pragma unroll
        for (int mf = 0; mf < 4; ++mf)
          a[ks][mf] = *(const bf16x8*)(g_A + (((tap + 1) * 4 + ks) * 8 + wm * 4 + mf) * 512 + l * 8);
      }
    }
  }

  // ---- epilogue: bias + lrelu*sqrt2 + clamp (slim VALU: lrelu = max(v, 0.2v),
  //      clamp -> v_med3); in-lane px pairs -> dense f32x2 NT stores ----
  float* outp = out + ((size_t)(n * CO) << 16);
  #pragma unroll
  for (int mf = 0; mf < 4; ++mf) {
    const int mg = wm * 4 + mf;
    const int py = mg >> 2, och = mg & 3;
    #pragma unroll
    for (int nf = 0; nf < 2; ++nf) {
      const int q = wn * 4 + nf * 2 + qh;
      const int y = 2 * (qb + q) + py;
      const int xd = 2 * (pb + p);
      #pragma unroll
      for (int rp = 0; rp < 8; ++rp) {
        const int oc = och * 16 + (rp & 1) + 4 * (rp >> 1) + 2 * kg2;
        const float bj = bias[oc];
        float v0 = acc[mf][nf][2 * rp]     + bj;
        float v1 = acc[mf][nf][2 * rp + 1] + bj;
        v0 = fmaxf(v0, 0.2f * v0) * 1.4142135623730951f;   // lrelu (alpha<1) as max
        v1 = fmaxf(v1, 0.2f * v1) * 1.4142135623730951f;
        v0 = fminf(256.f, fmaxf(-256.f, v0));              // -> v_med3
        v1 = fminf(256.f, fmaxf(-256.f, v1));
        f32x2 o; o[0] = v0; o[1] = v1;
        __builtin_nontemporal_store(o, (f32x2*)(outp + ((size_t)oc << 16) + y * 256 + xd));
      }
    }
  }
}

extern "C" void kernel_launch(void* const* d_in, const int* in_sizes, int n_in,
                              void* d_out, int out_size, void* d_ws, size_t ws_size,
                              hipStream_t stream) {
  const float* x    = (const float*)d_in[0];
  const float* w    = (const float*)d_in[1];
  const float* bias = (const float*)d_in[2];
  float* out = (float*)d_out;

  prep<<<2112, 256, 0, stream>>>(x, w);
  mfma_conv<<<dim3(128, NB), 256, 0, stream>>>(bias, out);
}